// Round 10
// baseline (748.638 us; speedup 1.0000x reference)
//
#include <hip/hip_runtime.h>
#include <hip/hip_bf16.h>

// Problem constants
#define B_ 64
#define S_ 128
#define C_ 32
#define D_ 512
#define V_ 20000

typedef float     f32x4  __attribute__((ext_vector_type(4)));
typedef _Float16  f16x8  __attribute__((ext_vector_type(8)));

#define AS1 __attribute__((address_space(1)))
#define AS3 __attribute__((address_space(3)))

// ---- workspace layout (bytes) ----
#define OFF_XH   0ull          // fp16 x   [8192][512]    8,388,608
#define OFF_UH   8388608ull    // fp16 U   [2048][512]    2,097,152
#define OFF_AW   10485760ull   // fp16 MFMA-swizzled weights = 3,145,728
#define OFF_CB   13631488ull   // f32 cb[2048]                8,192
#define OFF_PAD  13639680ull   // 8 KB pad (unused)
#define OFF_TWT  13647872ull   // f32 timew^T [64][512]     131,072
#define OFF_EMBH 13778944ull   // fp16 emb [20001][512]  20,481,024
#define OFF_TF   34259968ull   // fp16 tf [8192][512]     8,388,608
#define OFF_UX   42648576ull   // fp16 ux [8192][2048]   33,554,432
#define OFF_XB2  76203008ull   // u64 xb[128][2][16][8][64] = 16,777,216 (self-flagging)
                               // total 92,980,224 B

#define SENT32 0x7FFF7FFFu     // two fp16 NaNs — never produced by finite (h,c) pack

// ---------------- fused prep kernel (segmented by blockIdx) ----------------
// SEG0 [0,1): d_out init with bias
// SEG1 [1,4097): sentinel fill 16 MB
// SEG2 [4097,4098): cb = Wallb + Uallb
// SEG3 [4098,4130): timew^T
// SEG4 [4130,5154): U fp32->fp16
// SEG5 [5154,5922): W_all/W_d -> MFMA A-frag swizzle
// SEG6 [5922,25923): emb fp32->fp16
__global__ void k_prep_fused(
    const float* __restrict__ outb, float* __restrict__ outv,
    int4* __restrict__ fillp,
    const float* __restrict__ Wallb, const float* __restrict__ Uallb,
    float* __restrict__ cb,
    const float* __restrict__ tw, float* __restrict__ twt,
    const float* __restrict__ U, _Float16* __restrict__ uh,
    const float* __restrict__ Wall, const float* __restrict__ Wd,
    int4* __restrict__ AW,
    const float* __restrict__ emb, _Float16* __restrict__ eh)
{
    const int blk = blockIdx.x;
    const int t   = threadIdx.x;
    if (blk < 1) {
        if (t < 128) outv[t] = outb[t & 1];
    } else if (blk < 4097) {
        fillp[(blk - 1) * 256 + t] =
            int4{(int)SENT32, (int)SENT32, (int)SENT32, (int)SENT32};
    } else if (blk < 4098) {
        #pragma unroll
        for (int k = 0; k < 8; k++) {
            int i = t * 8 + k;
            cb[i] = Wallb[i] + Uallb[i];
        }
    } else if (blk < 4130) {
        int i2 = (blk - 4098) * 256 + t;
        #pragma unroll
        for (int k = 0; k < 4; k++) {
            int i = i2 * 4 + k;              // 0..32767
            twt[(i & 63) * 512 + (i >> 6)] = tw[i];
        }
    } else if (blk < 5154) {
        int i = (blk - 4130) * 256 + t;      // 0..262143 float4 groups
        float4 v = ((const float4*)U)[i];
        union { _Float16 h[4]; unsigned long long u; } pk;
        pk.h[0] = (_Float16)v.x; pk.h[1] = (_Float16)v.y;
        pk.h[2] = (_Float16)v.z; pk.h[3] = (_Float16)v.w;
        ((unsigned long long*)uh)[i] = pk.u;
    } else if (blk < 5922) {
        int i = (blk - 5154) * 256 + t;      // 0..196607
        int lane = i & 63;  int r = i >> 6;
        int kt = r & 15;    r >>= 4;
        int tile = r % 3;   r /= 3;
        int w = r & 7;      int m = r >> 3;
        int row16 = lane & 15, quad = lane >> 4;
        int q = tile * 2 + (row16 >> 3);
        int d = m * 64 + w * 8 + (row16 & 7);
        int k0 = kt * 32 + quad * 8;
        union { _Float16 h[8]; int4 v; } u;
        const float* src = nullptr;
        if (q < 4)       src = Wall + (size_t)(q * 512 + d) * 512 + k0;
        else if (q == 4) src = Wd   + (size_t)d * 512 + k0;
        #pragma unroll
        for (int j = 0; j < 8; j++) u.h[j] = src ? (_Float16)src[j] : (_Float16)0.f;
        AW[i] = u.v;
    } else {
        int i = (blk - 5922) * 256 + t;      // pair index, 0..5120255
        float2 v = ((const float2*)emb)[i];
        unsigned short hx = __builtin_bit_cast(unsigned short, (_Float16)v.x);
        unsigned short hy = __builtin_bit_cast(unsigned short, (_Float16)v.y);
        ((unsigned*)eh)[i] = (unsigned)hx | ((unsigned)hy << 16);
    }
}

// ---------------- embedding gather-sum (fp16 table) -> x fp16 ----------------
__global__ void k_embed2(const _Float16* __restrict__ embh, const int* __restrict__ seqs,
                         _Float16* __restrict__ xh)
{
    int bs = blockIdx.x;           // b*S + s
    int t  = threadIdx.x;          // 256 threads, 2 halves each
    __shared__ int rows[32];
    if (t < 32) {
        int r = seqs[(size_t)bs * C_ + t];
        rows[t] = (r < 0) ? V_ : r;
    }
    __syncthreads();
    float ax = 0.f, ay = 0.f;
    #pragma unroll 4
    for (int c = 0; c < C_; c++) {
        unsigned v = *(const unsigned*)(embh + (size_t)rows[c] * D_ + 2 * t);
        ax += (float)__builtin_bit_cast(_Float16, (unsigned short)v);
        ay += (float)__builtin_bit_cast(_Float16, (unsigned short)(v >> 16));
    }
    unsigned short hx = __builtin_bit_cast(unsigned short, (_Float16)ax);
    unsigned short hy = __builtin_bit_cast(unsigned short, (_Float16)ay);
    *(unsigned*)(xh + (size_t)bs * D_ + 2 * t) = (unsigned)hx | ((unsigned)hy << 16);
}

// ---------------- time feature: 16 bs per block, thread-per-d ----------------
__global__ __launch_bounds__(512) void k_tf2(
    const float* __restrict__ stime, const float* __restrict__ selw,
    const float* __restrict__ selb, const float* __restrict__ twT,
    const float* __restrict__ timeb, _Float16* __restrict__ tf)
{
    int bb = blockIdx.x;           // covers bs = bb*16 .. bb*16+15
    int t  = threadIdx.x;          // 512
    __shared__ float s1[16][64];
    for (int idx = t; idx < 1024; idx += 512) {
        int bl = idx >> 6, j = idx & 63;
        float tv = stime[bb * 16 + bl] * (1.0f / 180.0f);
        float u  = tv * selw[j] + selb[j];
        s1[bl][j] = 1.0f - tanhf(u * u);
    }
    __syncthreads();
    int d = t;
    float acc[16];
    float tb = timeb[d];
    #pragma unroll
    for (int l = 0; l < 16; l++) acc[l] = tb;
    for (int j = 0; j < 64; j++) {
        float wj = twT[j * 512 + d];
        #pragma unroll
        for (int l = 0; l < 16; l++) acc[l] = fmaf(s1[l][j], wj, acc[l]);
    }
    #pragma unroll
    for (int l = 0; l < 16; l++)
        tf[(size_t)(bb * 16 + l) * 512 + d] = (_Float16)acc[l];
}

// ---------------- ux GEMM v3: m97-style LDS-staged (unchanged from r9) --------
__device__ __forceinline__ void stage16(const _Float16* g, _Float16* l)
{
#if __has_builtin(__builtin_amdgcn_global_load_lds)
    __builtin_amdgcn_global_load_lds((const AS1 void*)g, (AS3 void*)l, 16, 0, 0);
#else
    *(int4*)l = *(const int4*)g;
#endif
}

__global__ __launch_bounds__(256, 4) void k_gemm3(const _Float16* __restrict__ A,
                                                  const _Float16* __restrict__ Bm,
                                                  _Float16* __restrict__ Cg)
{
    __shared__ __align__(16) _Float16 As[128 * 64];
    __shared__ __align__(16) _Float16 Bs[128 * 64];
    const int t = threadIdx.x;
    const int w = t >> 6, lane = t & 63;
    const int wm = w & 1, wn = w >> 1;
    const int m0 = blockIdx.y * 128, n0 = blockIdx.x * 128;
    const int r16 = lane & 15, quad = lane >> 4;

    const int srow = w * 8 + (lane >> 3);
    const int k8g  = (lane & 7) ^ ((lane >> 3) & 7);   // swizzled global k8
    const _Float16* ga = A  + (size_t)(m0 + srow) * 512 + k8g * 8;
    const _Float16* gb = Bm + (size_t)(n0 + srow) * 512 + k8g * 8;
    _Float16* la = As + srow * 64 + (lane & 7) * 8;
    _Float16* lb = Bs + srow * 64 + (lane & 7) * 8;

    f32x4 acc[4][4] = {};
    for (int k0 = 0; k0 < 512; k0 += 64) {
        __syncthreads();
        #pragma unroll
        for (int r = 0; r < 4; r++) {
            stage16(ga + k0 + (size_t)r * 32 * 512, la + r * 32 * 64);
            stage16(gb + k0 + (size_t)r * 32 * 512, lb + r * 32 * 64);
        }
        __syncthreads();
        #pragma unroll
        for (int sub = 0; sub < 2; sub++) {
            f16x8 af[4], bf[4];
            const int ksl = ((sub * 4 + quad) ^ (r16 & 7)) * 8;
            #pragma unroll
            for (int i = 0; i < 4; i++) {
                af[i] = *(const f16x8*)(As + (wm * 64 + i * 16 + r16) * 64 + ksl);
                bf[i] = *(const f16x8*)(Bs + (wn * 64 + i * 16 + r16) * 64 + ksl);
            }
            #pragma unroll
            for (int i = 0; i < 4; i++)
                #pragma unroll
                for (int j = 0; j < 4; j++)
                    acc[i][j] = __builtin_amdgcn_mfma_f32_16x16x32_f16(
                                    af[i], bf[j], acc[i][j], 0, 0, 0);
        }
    }
    #pragma unroll
    for (int i = 0; i < 4; i++)
        #pragma unroll
        for (int j = 0; j < 4; j++) {
            int row = m0 + wm * 64 + i * 16 + quad * 4;
            int col = n0 + wn * 64 + j * 16 + r16;
            _Float16* cp = Cg + (size_t)row * 2048 + col;
            #pragma unroll
            for (int rg = 0; rg < 4; rg++)
                cp[(size_t)rg * 2048] = (_Float16)acc[i][j][rg];
        }
}

// ---------------- fast transcendentals (v_exp + v_rcp) ----------------
__device__ __forceinline__ float fsigm(float x)
{
    return __builtin_amdgcn_rcpf(1.f + __expf(-x));
}
__device__ __forceinline__ float ftanh(float x)
{
    return 1.f - 2.f * __builtin_amdgcn_rcpf(1.f + __expf(2.f * x));
}

// ---------------- recurrence v8: pair-interleaved step pipeline --------------
// 16 groups x 8 members = 128 blocks. Group gid owns 4 batches b0=gid*4:
// pair 0 = {b0, b0+1}, pair 1 = {b0+2, b0+3}. Phase ph = 2s+pair: compute
// step s of that pair; the other pair's compute hides this pair's MALL
// publish->poll round trip. Per-pair protocol identical to proven round-6
// self-flagging exchange: xb[s][pair][gid][member][64] u64
// (= h0|c0<<16|h1<<32|c1<<48 per d), sentinel-prefilled.
__global__ __launch_bounds__(512, 2) void k_rnn8(
    const int4* __restrict__ AW,
    const float* __restrict__ cbv, const float* __restrict__ wdb,
    const _Float16* __restrict__ ux, const _Float16* __restrict__ tf,
    const float* __restrict__ outw,
    float* __restrict__ out,
    unsigned long long* __restrict__ xb64)
{
    const int t    = threadIdx.x;
    const int gid  = blockIdx.x >> 3;   // 0..15
    const int m    = blockIdx.x & 7;
    const int b0   = gid * 4;
    const int w    = t >> 6;            // wave id: consumer of member w, owner of d-octet w*8
    const int lane = t & 63;
    const int col  = lane & 15;
    const int quad = lane >> 4;

    int4 Af[48];
    {
        const int4* src = AW + (size_t)(m * 8 + w) * 3072;
        #pragma unroll
        for (int i = 0; i < 48; i++) Af[i] = src[i * 64 + lane];
    }

    __shared__ __align__(16) _Float16 xstg[2][4 * 544];   // [pair][4 streams+pad]
    __shared__ __align__(16) float cmat[8][4][48];
    __shared__ float pstg[4][64];

    const bool act = (lane < 16);
    const int  pb  = lane >> 3;        // batch-within-pair
    const int  pj  = lane & 7;
    const int  dl  = w * 8 + pj;
    const int  d   = m * 64 + dl;

    float cbf = 0, cbi = 0, cbo = 0, cbc = 0, bdv = 0;
    if (act) {
        cbf = cbv[d]; cbi = cbv[512 + d]; cbo = cbv[1024 + d]; cbc = cbv[1536 + d];
        bdv = wdb[d];
    }
    float c_reg[2] = {0.f, 0.f};           // per pair
    float pool[2]  = {-1e30f, -1e30f};
    const int dw = w * 64 + lane;

    for (int ph = 0; ph < 2 * S_; ph++) {
        const int pair = ph & 1;
        const int s    = ph >> 1;

        // ux/tf prefetch for (pair, s) — flies during the poll
        float uf = 0, ui = 0, uo = 0, uc = 0, tv = 0;
        if (act) {
            size_t bs = (size_t)(b0 + pair * 2 + pb) * S_ + s;
            const _Float16* up = ux + bs * 2048 + d;
            uf = (float)up[0];    ui = (float)up[512];
            uo = (float)up[1024]; uc = (float)up[1536];
            tv = (float)tf[bs * 512 + d];
        }

        // poll member w's self-flagging u64 for (pair, s)
        unsigned long long val = 0ull;
        if (s > 0) {
            const unsigned long long* src =
                xb64 + ((((size_t)s * 2 + pair) * 16 + gid) * 8 + w) * 64 + lane;
            int tries = 0;
            for (;;) {
                val = __hip_atomic_load(src, __ATOMIC_RELAXED,
                                        __HIP_MEMORY_SCOPE_AGENT);
                if ((unsigned)val != SENT32 && (unsigned)(val >> 32) != SENT32)
                    break;
                if (++tries > (1 << 22)) break;   // safety valve
            }
        }
        __syncthreads();              // B2: xstg[pair] readers (2 phases ago) done
        {
            _Float16* xs = xstg[pair];
            xs[0 * 544 + dw] = __builtin_bit_cast(_Float16, (unsigned short)(val));
            xs[2 * 544 + dw] = __builtin_bit_cast(_Float16, (unsigned short)(val >> 16));
            xs[1 * 544 + dw] = __builtin_bit_cast(_Float16, (unsigned short)(val >> 32));
            xs[3 * 544 + dw] = __builtin_bit_cast(_Float16, (unsigned short)(val >> 48));
        }
        __syncthreads();              // B1: staging visible

        // MFMA dot: 3 row-tiles x 16 k-tiles against this pair's h/c
        f32x4 a0 = {0, 0, 0, 0}, a1 = {0, 0, 0, 0}, a2 = {0, 0, 0, 0};
        {
            const _Float16* xs = xstg[pair];
            #pragma unroll
            for (int kt = 0; kt < 16; kt++) {
                f16x8 b = {};
                if (col < 4)
                    b = *(const f16x8*)(xs + col * 544 + kt * 32 + quad * 8);
                a0 = __builtin_amdgcn_mfma_f32_16x16x32_f16(
                         __builtin_bit_cast(f16x8, Af[kt]),      b, a0, 0, 0, 0);
                a1 = __builtin_amdgcn_mfma_f32_16x16x32_f16(
                         __builtin_bit_cast(f16x8, Af[16 + kt]), b, a1, 0, 0, 0);
                a2 = __builtin_amdgcn_mfma_f32_16x16x32_f16(
                         __builtin_bit_cast(f16x8, Af[32 + kt]), b, a2, 0, 0, 0);
            }
        }

        if (col < 4) {
            *(f32x4*)&cmat[w][col][ 0 + quad * 4] = a0;
            *(f32x4*)&cmat[w][col][16 + quad * 4] = a1;
            *(f32x4*)&cmat[w][col][32 + quad * 4] = a2;
        }

        if (act) {
            float f_  = cmat[w][pb][ 0 + pj];
            float i_  = cmat[w][pb][ 8 + pj];
            float o_  = cmat[w][pb][16 + pj];
            float g_  = cmat[w][pb][24 + pj];
            float wd_ = cmat[w][2 + pb][32 + pj];
            float gf = fsigm(f_ + cbf + uf);
            float gi = fsigm(i_ + cbi + ui);
            float go = fsigm(o_ + cbo + uo);
            float gc = fsigm(g_ + cbc + uc);
            float cs1  = ftanh(wd_ + bdv);
            float cadj = c_reg[pair] - cs1 + cs1 * tv;
            float cn   = gf * cadj + gi * gc;
            float hn   = go * ftanh(cn);
            c_reg[pair] = cn;
            pool[pair]  = fmaxf(pool[pair], hn);
            unsigned hh = __builtin_bit_cast(unsigned short, (_Float16)hn);
            unsigned cc = __builtin_bit_cast(unsigned short, (_Float16)cn);
            unsigned pk = hh | (cc << 16);
            unsigned other = __shfl(pk, lane + 8);   // lanes 0-7 fetch pb=1 pack
            if (pb == 0 && s != S_ - 1) {
                unsigned long long ov =
                    (unsigned long long)pk | ((unsigned long long)other << 32);
                unsigned long long* dst =
                    xb64 + ((((size_t)(s + 1) * 2 + pair) * 16 + gid) * 8 + m) * 64 + dl;
                __hip_atomic_store(dst, ov, __ATOMIC_RELAXED,
                                   __HIP_MEMORY_SCOPE_AGENT);
            }
        }
    }

    // pooled epilogue -> atomicAdd into bias-initialized d_out
    if (act) { pstg[0 + pb][dl] = pool[0]; pstg[2 + pb][dl] = pool[1]; }
    __syncthreads();
    if (t < 256) {
        int b = t >> 6, l = t & 63;    // b: 0,1 = pair0; 2,3 = pair1 (matches b0+b)
        float pv = pstg[b][l];
        int dg = m * 64 + l;
        float p0 = pv * outw[dg], p1 = pv * outw[512 + dg];
        #pragma unroll
        for (int off = 32; off > 0; off >>= 1) {
            p0 += __shfl_down(p0, off);
            p1 += __shfl_down(p1, off);
        }
        if (l == 0) {
            atomicAdd(&out[2 * (b0 + b)],     p0);
            atomicAdd(&out[2 * (b0 + b) + 1], p1);
        }
    }
}

// ---------------- launch ----------------
extern "C" void kernel_launch(void* const* d_in, const int* in_sizes, int n_in,
                              void* d_out, int out_size, void* d_ws, size_t ws_size,
                              hipStream_t stream)
{
    const float* emb   = (const float*)d_in[0];
    const float* Wall  = (const float*)d_in[1];
    const float* Wallb = (const float*)d_in[2];
    const float* Uall  = (const float*)d_in[3];
    const float* Uallb = (const float*)d_in[4];
    const float* Wdw   = (const float*)d_in[5];
    const float* Wdb   = (const float*)d_in[6];
    const float* selw  = (const float*)d_in[7];
    const float* selb  = (const float*)d_in[8];
    const float* timew = (const float*)d_in[9];
    const float* timeb = (const float*)d_in[10];
    const float* outw  = (const float*)d_in[11];
    const float* outb  = (const float*)d_in[12];
    const float* stime = (const float*)d_in[13];
    const int*   seqs  = (const int*)d_in[14];
    float* out = (float*)d_out;
    char*  ws  = (char*)d_ws;

    _Float16* xh   = (_Float16*)(ws + OFF_XH);
    _Float16* uh   = (_Float16*)(ws + OFF_UH);
    int4*     aw   = (int4*)(ws + OFF_AW);
    float*    cbp  = (float*)(ws + OFF_CB);
    float*    twt  = (float*)(ws + OFF_TWT);
    _Float16* eh   = (_Float16*)(ws + OFF_EMBH);
    _Float16* tfp  = (_Float16*)(ws + OFF_TF);
    _Float16* uxp  = (_Float16*)(ws + OFF_UX);
    unsigned long long* xb = (unsigned long long*)(ws + OFF_XB2);

    k_prep_fused<<<25923, 256, 0, stream>>>(
        outb, out, (int4*)(ws + OFF_XB2),
        Wallb, Uallb, cbp,
        timew, twt,
        Uall, uh,
        Wall, Wdw, aw,
        emb, eh);
    k_embed2 <<<B_ * S_, 256, 0, stream>>>(eh, seqs, xh);
    k_tf2    <<<512,     512, 0, stream>>>(stime, selw, selb, twt, timeb, tfp);
    k_gemm3  <<<dim3(16, 64), 256, 0, stream>>>(xh, uh, uxp);
    k_rnn8   <<<128,     512, 0, stream>>>(aw, cbp, Wdb, uxp, tfp, outw, out, xb);
}

// Round 11
// 486.657 us; speedup vs baseline: 1.5383x; 1.5383x over previous
//
#include <hip/hip_runtime.h>
#include <hip/hip_bf16.h>

// Problem constants
#define B_ 64
#define S_ 128
#define C_ 32
#define D_ 512
#define V_ 20000

typedef float     f32x4  __attribute__((ext_vector_type(4)));
typedef _Float16  f16x8  __attribute__((ext_vector_type(8)));

#define AS1 __attribute__((address_space(1)))
#define AS3 __attribute__((address_space(3)))

// ---- workspace layout (bytes) ----
#define OFF_XH   0ull          // fp16 x   [8192][512]    8,388,608
#define OFF_UH   8388608ull    // fp16 U   [2048][512]    2,097,152
#define OFF_AW   10485760ull   // fp16 MFMA-swizzled weights = 3,145,728
#define OFF_CB   13631488ull   // f32 cb[2048]                8,192
#define OFF_PAD  13639680ull   // 8 KB pad (unused)
#define OFF_TWT  13647872ull   // f32 timew^T [64][512]     131,072
#define OFF_EMBH 13778944ull   // fp16 emb [20001][512]  20,481,024
#define OFF_TF   34259968ull   // fp16 tf [8192][512]     8,388,608
#define OFF_UX   42648576ull   // fp16 ux [8192][2048]   33,554,432
#define OFF_XB2  76203008ull   // u64 xb[128][32][8][64] = 16,777,216 (self-flagging)
                               // total 92,980,224 B

#define SENT32 0x7FFF7FFFu     // two fp16 NaNs — never produced by finite (h,c) pack

// ---------------- fused prep kernel (segmented by blockIdx) ----------------
// SEG0 [0,1): d_out init with bias
// SEG1 [1,4097): sentinel fill 16 MB
// SEG2 [4097,4098): cb = Wallb + Uallb
// SEG3 [4098,4130): timew^T
// SEG4 [4130,5154): U fp32->fp16
// SEG5 [5154,5922): W_all/W_d -> MFMA A-frag swizzle
// SEG6 [5922,25923): emb fp32->fp16
__global__ void k_prep_fused(
    const float* __restrict__ outb, float* __restrict__ outv,
    int4* __restrict__ fillp,
    const float* __restrict__ Wallb, const float* __restrict__ Uallb,
    float* __restrict__ cb,
    const float* __restrict__ tw, float* __restrict__ twt,
    const float* __restrict__ U, _Float16* __restrict__ uh,
    const float* __restrict__ Wall, const float* __restrict__ Wd,
    int4* __restrict__ AW,
    const float* __restrict__ emb, _Float16* __restrict__ eh)
{
    const int blk = blockIdx.x;
    const int t   = threadIdx.x;
    if (blk < 1) {
        if (t < 128) outv[t] = outb[t & 1];
    } else if (blk < 4097) {
        fillp[(blk - 1) * 256 + t] =
            int4{(int)SENT32, (int)SENT32, (int)SENT32, (int)SENT32};
    } else if (blk < 4098) {
        #pragma unroll
        for (int k = 0; k < 8; k++) {
            int i = t * 8 + k;
            cb[i] = Wallb[i] + Uallb[i];
        }
    } else if (blk < 4130) {
        int i2 = (blk - 4098) * 256 + t;
        #pragma unroll
        for (int k = 0; k < 4; k++) {
            int i = i2 * 4 + k;              // 0..32767
            twt[(i & 63) * 512 + (i >> 6)] = tw[i];
        }
    } else if (blk < 5154) {
        int i = (blk - 4130) * 256 + t;      // 0..262143 float4 groups
        float4 v = ((const float4*)U)[i];
        union { _Float16 h[4]; unsigned long long u; } pk;
        pk.h[0] = (_Float16)v.x; pk.h[1] = (_Float16)v.y;
        pk.h[2] = (_Float16)v.z; pk.h[3] = (_Float16)v.w;
        ((unsigned long long*)uh)[i] = pk.u;
    } else if (blk < 5922) {
        int i = (blk - 5154) * 256 + t;      // 0..196607
        int lane = i & 63;  int r = i >> 6;
        int kt = r & 15;    r >>= 4;
        int tile = r % 3;   r /= 3;
        int w = r & 7;      int m = r >> 3;
        int row16 = lane & 15, quad = lane >> 4;
        int q = tile * 2 + (row16 >> 3);
        int d = m * 64 + w * 8 + (row16 & 7);
        int k0 = kt * 32 + quad * 8;
        union { _Float16 h[8]; int4 v; } u;
        const float* src = nullptr;
        if (q < 4)       src = Wall + (size_t)(q * 512 + d) * 512 + k0;
        else if (q == 4) src = Wd   + (size_t)d * 512 + k0;
        #pragma unroll
        for (int j = 0; j < 8; j++) u.h[j] = src ? (_Float16)src[j] : (_Float16)0.f;
        AW[i] = u.v;
    } else {
        int i = (blk - 5922) * 256 + t;      // pair index, 0..5120255
        float2 v = ((const float2*)emb)[i];
        unsigned short hx = __builtin_bit_cast(unsigned short, (_Float16)v.x);
        unsigned short hy = __builtin_bit_cast(unsigned short, (_Float16)v.y);
        ((unsigned*)eh)[i] = (unsigned)hx | ((unsigned)hy << 16);
    }
}

// ---------------- embedding gather-sum (fp16 table) -> x fp16 ----------------
__global__ void k_embed2(const _Float16* __restrict__ embh, const int* __restrict__ seqs,
                         _Float16* __restrict__ xh)
{
    int bs = blockIdx.x;           // b*S + s
    int t  = threadIdx.x;          // 256 threads, 2 halves each
    __shared__ int rows[32];
    if (t < 32) {
        int r = seqs[(size_t)bs * C_ + t];
        rows[t] = (r < 0) ? V_ : r;
    }
    __syncthreads();
    float ax = 0.f, ay = 0.f;
    #pragma unroll 4
    for (int c = 0; c < C_; c++) {
        unsigned v = *(const unsigned*)(embh + (size_t)rows[c] * D_ + 2 * t);
        ax += (float)__builtin_bit_cast(_Float16, (unsigned short)v);
        ay += (float)__builtin_bit_cast(_Float16, (unsigned short)(v >> 16));
    }
    unsigned short hx = __builtin_bit_cast(unsigned short, (_Float16)ax);
    unsigned short hy = __builtin_bit_cast(unsigned short, (_Float16)ay);
    *(unsigned*)(xh + (size_t)bs * D_ + 2 * t) = (unsigned)hx | ((unsigned)hy << 16);
}

// ---------------- time feature: 16 bs per block, thread-per-d ----------------
__global__ __launch_bounds__(512) void k_tf2(
    const float* __restrict__ stime, const float* __restrict__ selw,
    const float* __restrict__ selb, const float* __restrict__ twT,
    const float* __restrict__ timeb, _Float16* __restrict__ tf)
{
    int bb = blockIdx.x;           // covers bs = bb*16 .. bb*16+15
    int t  = threadIdx.x;          // 512
    __shared__ float s1[16][64];
    for (int idx = t; idx < 1024; idx += 512) {
        int bl = idx >> 6, j = idx & 63;
        float tv = stime[bb * 16 + bl] * (1.0f / 180.0f);
        float u  = tv * selw[j] + selb[j];
        s1[bl][j] = 1.0f - tanhf(u * u);
    }
    __syncthreads();
    int d = t;
    float acc[16];
    float tb = timeb[d];
    #pragma unroll
    for (int l = 0; l < 16; l++) acc[l] = tb;
    for (int j = 0; j < 64; j++) {
        float wj = twT[j * 512 + d];
        #pragma unroll
        for (int l = 0; l < 16; l++) acc[l] = fmaf(s1[l][j], wj, acc[l]);
    }
    #pragma unroll
    for (int l = 0; l < 16; l++)
        tf[(size_t)(bb * 16 + l) * 512 + d] = (_Float16)acc[l];
}

// ---------------- ux GEMM v3: m97-style LDS-staged (unchanged from r9) --------
__device__ __forceinline__ void stage16(const _Float16* g, _Float16* l)
{
#if __has_builtin(__builtin_amdgcn_global_load_lds)
    __builtin_amdgcn_global_load_lds((const AS1 void*)g, (AS3 void*)l, 16, 0, 0);
#else
    *(int4*)l = *(const int4*)g;
#endif
}

__global__ __launch_bounds__(256, 4) void k_gemm3(const _Float16* __restrict__ A,
                                                  const _Float16* __restrict__ Bm,
                                                  _Float16* __restrict__ Cg)
{
    __shared__ __align__(16) _Float16 As[128 * 64];
    __shared__ __align__(16) _Float16 Bs[128 * 64];
    const int t = threadIdx.x;
    const int w = t >> 6, lane = t & 63;
    const int wm = w & 1, wn = w >> 1;
    const int m0 = blockIdx.y * 128, n0 = blockIdx.x * 128;
    const int r16 = lane & 15, quad = lane >> 4;

    const int srow = w * 8 + (lane >> 3);
    const int k8g  = (lane & 7) ^ ((lane >> 3) & 7);   // swizzled global k8
    const _Float16* ga = A  + (size_t)(m0 + srow) * 512 + k8g * 8;
    const _Float16* gb = Bm + (size_t)(n0 + srow) * 512 + k8g * 8;
    _Float16* la = As + srow * 64 + (lane & 7) * 8;
    _Float16* lb = Bs + srow * 64 + (lane & 7) * 8;

    f32x4 acc[4][4] = {};
    for (int k0 = 0; k0 < 512; k0 += 64) {
        __syncthreads();
        #pragma unroll
        for (int r = 0; r < 4; r++) {
            stage16(ga + k0 + (size_t)r * 32 * 512, la + r * 32 * 64);
            stage16(gb + k0 + (size_t)r * 32 * 512, lb + r * 32 * 64);
        }
        __syncthreads();
        #pragma unroll
        for (int sub = 0; sub < 2; sub++) {
            f16x8 af[4], bf[4];
            const int ksl = ((sub * 4 + quad) ^ (r16 & 7)) * 8;
            #pragma unroll
            for (int i = 0; i < 4; i++) {
                af[i] = *(const f16x8*)(As + (wm * 64 + i * 16 + r16) * 64 + ksl);
                bf[i] = *(const f16x8*)(Bs + (wn * 64 + i * 16 + r16) * 64 + ksl);
            }
            #pragma unroll
            for (int i = 0; i < 4; i++)
                #pragma unroll
                for (int j = 0; j < 4; j++)
                    acc[i][j] = __builtin_amdgcn_mfma_f32_16x16x32_f16(
                                    af[i], bf[j], acc[i][j], 0, 0, 0);
        }
    }
    #pragma unroll
    for (int i = 0; i < 4; i++)
        #pragma unroll
        for (int j = 0; j < 4; j++) {
            int row = m0 + wm * 64 + i * 16 + quad * 4;
            int col = n0 + wn * 64 + j * 16 + r16;
            _Float16* cp = Cg + (size_t)row * 2048 + col;
            #pragma unroll
            for (int rg = 0; rg < 4; rg++)
                cp[(size_t)rg * 2048] = (_Float16)acc[i][j][rg];
        }
}

// ---------------- fast transcendentals (v_exp + v_rcp) ----------------
__device__ __forceinline__ float fsigm(float x)
{
    return __builtin_amdgcn_rcpf(1.f + __expf(-x));
}
__device__ __forceinline__ float ftanh(float x)
{
    return 1.f - 2.f * __builtin_amdgcn_rcpf(1.f + __expf(2.f * x));
}

// ---------------- recurrence v9: round-7 structure, SINGLE barrier per step ----
// 32 groups x 8 members = 256 blocks, 2 batches/group (the proven 299-us shape).
// Change vs r7: xstg double-buffered by step parity -> the B2 (WAR) barrier is
// GONE. Safety: a wave writes xstg[(s+2)&1] (same buffer as step s) only after
// passing B1(s+1), and reaching B1(s+1) requires (program order) having finished
// its step-s xstg reads — distance-2 reuse is barrier-protected with ONE barrier.
// Per-step chain: publish (fire) -> poll (covers own store drain) -> stage ->
// B1 -> MFMA/pointwise.
__global__ __launch_bounds__(512, 2) void k_rnn9(
    const int4* __restrict__ AW,
    const float* __restrict__ cbv, const float* __restrict__ wdb,
    const _Float16* __restrict__ ux, const _Float16* __restrict__ tf,
    const float* __restrict__ outw,
    float* __restrict__ out,
    unsigned long long* __restrict__ xb64)
{
    const int t    = threadIdx.x;
    const int gid  = blockIdx.x >> 3;
    const int m    = blockIdx.x & 7;
    const int b0   = gid * 2;
    const int w    = t >> 6;           // wave id: consumer of member w, owner of d-octet w*8
    const int lane = t & 63;
    const int col  = lane & 15;
    const int quad = lane >> 4;

    int4 Af[48];
    {
        const int4* src = AW + (size_t)(m * 8 + w) * 3072;
        #pragma unroll
        for (int i = 0; i < 48; i++) Af[i] = src[i * 64 + lane];
    }

    __shared__ __align__(16) _Float16 xstg[2][4 * 544];   // [parity][4 streams+pad]
    __shared__ __align__(16) float cmat[8][4][48];
    __shared__ float pstg[2][64];

    const bool act = (lane < 16);
    const int  pb  = lane >> 3;
    const int  pj  = lane & 7;
    const int  dl  = w * 8 + pj;
    const int  d   = m * 64 + dl;

    float cbf = 0, cbi = 0, cbo = 0, cbc = 0, bdv = 0;
    if (act) {
        cbf = cbv[d]; cbi = cbv[512 + d]; cbo = cbv[1024 + d]; cbc = cbv[1536 + d];
        bdv = wdb[d];
    }
    float c_reg = 0.f, pool = -1e30f;
    const int dw = w * 64 + lane;

    for (int s = 0; s < S_; s++) {
        const int sp = s & 1;

        // ux/tf prefetch — flies during the poll
        float uf = 0, ui = 0, uo = 0, uc = 0, tv = 0;
        if (act) {
            size_t bs = (size_t)(b0 + pb) * S_ + s;
            const _Float16* up = ux + bs * 2048 + d;
            uf = (float)up[0];    ui = (float)up[512];
            uo = (float)up[1024]; uc = (float)up[1536];
            tv = (float)tf[bs * 512 + d];
        }

        // poll member w's self-flagging u64 (own step-s-1 publish drains under this)
        unsigned long long val = 0ull;
        if (s > 0) {
            const unsigned long long* src =
                xb64 + (((size_t)s * 32 + gid) * 8 + w) * 64 + lane;
            int tries = 0;
            for (;;) {
                val = __hip_atomic_load(src, __ATOMIC_RELAXED,
                                        __HIP_MEMORY_SCOPE_AGENT);
                if ((unsigned)val != SENT32 && (unsigned)(val >> 32) != SENT32)
                    break;
                if (++tries > (1 << 22)) break;   // safety valve
            }
        }
        // stage into parity buffer (no WAR barrier needed: distance-2 reuse is
        // blocked by B1 of the intervening step, see header comment)
        {
            _Float16* xs = xstg[sp];
            xs[0 * 544 + dw] = __builtin_bit_cast(_Float16, (unsigned short)(val));
            xs[2 * 544 + dw] = __builtin_bit_cast(_Float16, (unsigned short)(val >> 16));
            xs[1 * 544 + dw] = __builtin_bit_cast(_Float16, (unsigned short)(val >> 32));
            xs[3 * 544 + dw] = __builtin_bit_cast(_Float16, (unsigned short)(val >> 48));
        }
        __syncthreads();              // B1: staging visible (the ONLY barrier/step)

        // MFMA dot: 3 row-tiles x 16 k-tiles
        f32x4 a0 = {0, 0, 0, 0}, a1 = {0, 0, 0, 0}, a2 = {0, 0, 0, 0};
        {
            const _Float16* xs = xstg[sp];
            #pragma unroll
            for (int kt = 0; kt < 16; kt++) {
                f16x8 b = {};
                if (col < 4)
                    b = *(const f16x8*)(xs + col * 544 + kt * 32 + quad * 8);
                a0 = __builtin_amdgcn_mfma_f32_16x16x32_f16(
                         __builtin_bit_cast(f16x8, Af[kt]),      b, a0, 0, 0, 0);
                a1 = __builtin_amdgcn_mfma_f32_16x16x32_f16(
                         __builtin_bit_cast(f16x8, Af[16 + kt]), b, a1, 0, 0, 0);
                a2 = __builtin_amdgcn_mfma_f32_16x16x32_f16(
                         __builtin_bit_cast(f16x8, Af[32 + kt]), b, a2, 0, 0, 0);
            }
        }

        if (col < 4) {
            *(f32x4*)&cmat[w][col][ 0 + quad * 4] = a0;
            *(f32x4*)&cmat[w][col][16 + quad * 4] = a1;
            *(f32x4*)&cmat[w][col][32 + quad * 4] = a2;
        }

        if (act) {
            float f_  = cmat[w][pb][ 0 + pj];
            float i_  = cmat[w][pb][ 8 + pj];
            float o_  = cmat[w][pb][16 + pj];
            float g_  = cmat[w][pb][24 + pj];
            float wd_ = cmat[w][2 + pb][32 + pj];
            float gf = fsigm(f_ + cbf + uf);
            float gi = fsigm(i_ + cbi + ui);
            float go = fsigm(o_ + cbo + uo);
            float gc = fsigm(g_ + cbc + uc);
            float cs1  = ftanh(wd_ + bdv);
            float cadj = c_reg - cs1 + cs1 * tv;
            float cn   = gf * cadj + gi * gc;
            float hn   = go * ftanh(cn);
            c_reg = cn;
            pool  = fmaxf(pool, hn);
            unsigned hh = __builtin_bit_cast(unsigned short, (_Float16)hn);
            unsigned cc = __builtin_bit_cast(unsigned short, (_Float16)cn);
            unsigned pk = hh | (cc << 16);
            unsigned other = __shfl(pk, lane + 8);   // lanes 0-7 fetch pb=1 pack
            if (pb == 0 && s != S_ - 1) {
                unsigned long long ov =
                    (unsigned long long)pk | ((unsigned long long)other << 32);
                unsigned long long* dst =
                    xb64 + (((size_t)(s + 1) * 32 + gid) * 8 + m) * 64 + dl;
                __hip_atomic_store(dst, ov, __ATOMIC_RELAXED,
                                   __HIP_MEMORY_SCOPE_AGENT);
            }
        }
    }

    // pooled epilogue -> atomicAdd into bias-initialized d_out
    if (act) pstg[pb][dl] = pool;
    __syncthreads();
    if (t < 128) {
        int b = t >> 6, l = t & 63;
        float pv = pstg[b][l];
        int dg = m * 64 + l;
        float p0 = pv * outw[dg], p1 = pv * outw[512 + dg];
        #pragma unroll
        for (int off = 32; off > 0; off >>= 1) {
            p0 += __shfl_down(p0, off);
            p1 += __shfl_down(p1, off);
        }
        if (l == 0) {
            atomicAdd(&out[2 * (b0 + b)],     p0);
            atomicAdd(&out[2 * (b0 + b) + 1], p1);
        }
    }
}

// ---------------- launch ----------------
extern "C" void kernel_launch(void* const* d_in, const int* in_sizes, int n_in,
                              void* d_out, int out_size, void* d_ws, size_t ws_size,
                              hipStream_t stream)
{
    const float* emb   = (const float*)d_in[0];
    const float* Wall  = (const float*)d_in[1];
    const float* Wallb = (const float*)d_in[2];
    const float* Uall  = (const float*)d_in[3];
    const float* Uallb = (const float*)d_in[4];
    const float* Wdw   = (const float*)d_in[5];
    const float* Wdb   = (const float*)d_in[6];
    const float* selw  = (const float*)d_in[7];
    const float* selb  = (const float*)d_in[8];
    const float* timew = (const float*)d_in[9];
    const float* timeb = (const float*)d_in[10];
    const float* outw  = (const float*)d_in[11];
    const float* outb  = (const float*)d_in[12];
    const float* stime = (const float*)d_in[13];
    const int*   seqs  = (const int*)d_in[14];
    float* out = (float*)d_out;
    char*  ws  = (char*)d_ws;

    _Float16* xh   = (_Float16*)(ws + OFF_XH);
    _Float16* uh   = (_Float16*)(ws + OFF_UH);
    int4*     aw   = (int4*)(ws + OFF_AW);
    float*    cbp  = (float*)(ws + OFF_CB);
    float*    twt  = (float*)(ws + OFF_TWT);
    _Float16* eh   = (_Float16*)(ws + OFF_EMBH);
    _Float16* tfp  = (_Float16*)(ws + OFF_TF);
    _Float16* uxp  = (_Float16*)(ws + OFF_UX);
    unsigned long long* xb = (unsigned long long*)(ws + OFF_XB2);

    k_prep_fused<<<25923, 256, 0, stream>>>(
        outb, out, (int4*)(ws + OFF_XB2),
        Wallb, Uallb, cbp,
        timew, twt,
        Uall, uh,
        Wall, Wdw, aw,
        emb, eh);
    k_embed2 <<<B_ * S_, 256, 0, stream>>>(eh, seqs, xh);
    k_tf2    <<<512,     512, 0, stream>>>(stime, selw, selb, twt, timeb, tfp);
    k_gemm3  <<<dim3(16, 64), 256, 0, stream>>>(xh, uh, uxp);
    k_rnn9   <<<256,     512, 0, stream>>>(aw, cbp, Wdb, uxp, tfp, outw, out, xb);
}